// Round 1
// baseline (4078.402 us; speedup 1.0000x reference)
//
#include <hip/hip_runtime.h>

typedef unsigned short ushort_t;
typedef _Float16 h2 __attribute__((ext_vector_type(2)));
typedef _Float16 h8 __attribute__((ext_vector_type(8)));

#define T_TOT 2048
#define B_    64
#define H3_   768

__device__ __forceinline__ float bf2f(ushort_t u){
  return __uint_as_float(((unsigned)u) << 16);
}
__device__ __forceinline__ ushort_t f2bf(float f){
  unsigned u = __float_as_uint(f);
  u += 0x7FFFu + ((u >> 16) & 1u);
  return (ushort_t)(u >> 16);
}
#if __has_builtin(__builtin_amdgcn_fdot2)
__device__ __forceinline__ float fdot2_(h2 a, h2 b, float c){
  return __builtin_amdgcn_fdot2(a, b, c, false);
}
#else
__device__ __forceinline__ float fdot2_(h2 a, h2 b, float c){
  return c + (float)a[0]*(float)b[0] + (float)a[1]*(float)b[1];
}
#endif
__device__ __forceinline__ float sigm_(float x){ return 1.0f/(1.0f + __expf(-x)); }
__device__ __forceinline__ float tanh_(float x){ float e=__expf(2.0f*x); return 1.0f - 2.0f/(e+1.0f); }

// xor-1 neighbor add via DPP quad_perm [1,0,3,2] — replaces ds_bpermute shuffle
// (lgkm latency) with a 1-cycle VALU op. All lanes active at call sites.
__device__ __forceinline__ float xor1_add(float x){
  int y = __builtin_amdgcn_mov_dpp(__float_as_int(x), 0xB1, 0xF, 0xF, true);
  return x + __int_as_float(y);
}

// Barrier that waits only on LDS traffic. __syncthreads() emits
// s_waitcnt vmcnt(0) lgkmcnt(0) + s_barrier, which drains the per-step ys
// global stores (HBM ack ~300-600cy) on the critical path 2048 times.
// Only lgkmcnt(0) is needed for hbuf double-buffer visibility.
__device__ __forceinline__ void barrier_lgkm(){
  asm volatile("s_waitcnt lgkmcnt(0)" ::: "memory");
  __builtin_amdgcn_s_barrier();
}

template<int F32>
__device__ __forceinline__ float ldf(const void* p, size_t i){
  if (F32) return ((const float*)p)[i];
  return bf2f(((const ushort_t*)p)[i]);
}

// Lane owns columns {cc, 256+cc, 512+cc} and k-half hh of a [256,768] matrix:
// 192 packed-f16 registers.
template<int F32>
__device__ __forceinline__ void load_w_t(const void* __restrict__ W, int cc, int hh,
                                         h2* wr, h2* wz, h2* wn){
#pragma unroll
  for (int i = 0; i < 64; i++){
    size_t r0 = (size_t)(hh * 128 + 2 * i) * H3_;
    size_t r1 = r0 + H3_;
    wr[i][0] = (_Float16)ldf<F32>(W, r0 + cc);
    wr[i][1] = (_Float16)ldf<F32>(W, r1 + cc);
    wz[i][0] = (_Float16)ldf<F32>(W, r0 + 256 + cc);
    wz[i][1] = (_Float16)ldf<F32>(W, r1 + 256 + cc);
    wn[i][0] = (_Float16)ldf<F32>(W, r0 + 512 + cc);
    wn[i][1] = (_Float16)ldf<F32>(W, r1 + 512 + cc);
  }
}

// 128-MAC-per-gate half dot. hp: 16 x ds_read_b128 wave-uniform broadcast.
__device__ __forceinline__ void dot_block(const h8* hp, const h2* wr, const h2* wz,
                                          const h2* wn, float& ar, float& az, float& an){
#pragma unroll
  for (int i = 0; i < 16; i++){
    h8 v = hp[i];
#pragma unroll
    for (int u = 0; u < 4; u++){
      h2 p; p[0] = v[2 * u]; p[1] = v[2 * u + 1];
      int j = 4 * i + u;
      ar = fdot2_(p, wr[j], ar);
      az = fdot2_(p, wz[j], az);
      an = fdot2_(p, wn[j], an);
    }
  }
}

// Dtype probe: even halfword indices of Wh decode to plausible bf16 exponents
// iff the buffer really is bf16 (f32 low-mantissa halves are random).
__global__ void dtype_probe(const void* __restrict__ W, int* __restrict__ flag){
  const int lane = threadIdx.x;   // 64 threads, 1 wave
  const ushort_t* p = (const ushort_t*)W;
  int s0, s1;
  {
    ushort_t h = p[4 * lane];
    int e = (h >> 7) & 0xFF;
    s0 = (e == 0 || (e >= 80 && e <= 141)) ? 1 : 0;
  }
  {
    ushort_t h = p[4 * lane + 2];
    int e = (h >> 7) & 0xFF;
    s1 = (e == 0 || (e >= 80 && e <= 141)) ? 1 : 0;
  }
  unsigned long long m0 = __ballot(s0);
  unsigned long long m1 = __ballot(s1);
  if (lane == 0){
    int sane = __popcll(m0) + __popcll(m1);          // of 128 samples
    *flag = (sane >= 96) ? 0 : 1;                    // 0 = bf16, 1 = f32
  }
}

// Phase 1: xi rows = xs rows @ Wi (f16 out). Single LDS buffer, 2 barriers/iter.
__global__ __launch_bounds__(512, 2) void gru_xproj(
    const void* __restrict__ xs, const void* __restrict__ Wi,
    _Float16* __restrict__ xi, const int* __restrict__ flag, int t0, int Tc)
{
  const int lane = threadIdx.x;
  const int cc = lane >> 1, hh = lane & 1;
  const int f32 = *flag;

  h2 wr[64], wz[64], wn[64];
  if (f32) load_w_t<1>(Wi, cc, hh, wr, wz, wn);
  else     load_w_t<0>(Wi, cc, hh, wr, wz, wn);

  __shared__ __align__(16) _Float16 xb[4][256];
  _Float16* xf = &xb[0][0];
  const int groups = Tc * 16;                        // 4 rows per group
  for (int g = blockIdx.x; g < groups; g += gridDim.x){
    const size_t base = ((size_t)t0 * 64 + (size_t)g * 4) * 256;
    if (f32){
      xf[lane]       = (_Float16)((const float*)xs)[base + lane];
      xf[lane + 512] = (_Float16)((const float*)xs)[base + lane + 512];
    } else {
      xf[lane]       = (_Float16)bf2f(((const ushort_t*)xs)[base + lane]);
      xf[lane + 512] = (_Float16)bf2f(((const ushort_t*)xs)[base + lane + 512]);
    }
    barrier_lgkm();                                  // xf writes visible; no vmcnt drain
#pragma unroll
    for (int rr = 0; rr < 4; rr++){
      const h8* hp = (const h8*)&xb[rr][hh * 128];
      float ar = 0.f, az = 0.f, an = 0.f;
      dot_block(hp, wr, wz, wn, ar, az, an);
      float Sr = xor1_add(ar);
      float Sz = xor1_add(az);
      float Sn = xor1_add(an);
      if (hh == 0){
        _Float16* o = xi + ((size_t)g * 4 + rr) * H3_;
        o[cc]       = (_Float16)Sr;
        o[256 + cc] = (_Float16)Sz;
        o[512 + cc] = (_Float16)Sn;
      }
    }
    barrier_lgkm();                                  // reads done before next overwrite
  }
}

// Phase 2: 64 blocks (one per batch), Wh register-resident, h double-buffered
// in LDS, one barrier per step. Critical-path trims vs previous version:
// lgkm-only barrier (ys stores no longer drained per step), DPP gate reduce,
// xi prefetched one step ahead.
__global__ __launch_bounds__(512, 2) void gru_rec(
    const _Float16* __restrict__ xi, const void* __restrict__ Wh,
    const void* __restrict__ bh, const void* __restrict__ bin,
    const void* __restrict__ c0, float* __restrict__ h_state,
    void* __restrict__ dout, const int* __restrict__ flag, int t0, int Tc)
{
  const int lane = threadIdx.x;
  const int cc = lane >> 1, hh = lane & 1;
  const int b = blockIdx.x;
  const int f32 = *flag;

  h2 wr[64], wz[64], wn[64];
  if (f32) load_w_t<1>(Wh, cc, hh, wr, wz, wn);
  else     load_w_t<0>(Wh, cc, hh, wr, wz, wn);

  float br, bz, bn, bi;
  if (f32){
    br = ((const float*)bh)[cc];       bz = ((const float*)bh)[256 + cc];
    bn = ((const float*)bh)[512 + cc]; bi = ((const float*)bin)[cc];
  } else {
    br = bf2f(((const ushort_t*)bh)[cc]);       bz = bf2f(((const ushort_t*)bh)[256 + cc]);
    bn = bf2f(((const ushort_t*)bh)[512 + cc]); bi = bf2f(((const ushort_t*)bin)[cc]);
  }

  __shared__ __align__(16) _Float16 hbuf[2][256];

  float hprev;
  if (t0 == 0) hprev = f32 ? ((const float*)c0)[b * 256 + cc]
                           : bf2f(((const ushort_t*)c0)[b * 256 + cc]);
  else         hprev = h_state[b * 256 + cc];
  if (lane < 256){
    float hj;
    if (t0 == 0) hj = f32 ? ((const float*)c0)[b * 256 + lane]
                          : bf2f(((const ushort_t*)c0)[b * 256 + lane]);
    else         hj = h_state[b * 256 + lane];
    hbuf[0][lane] = (_Float16)hj;
  }

  ushort_t* outb = (ushort_t*)dout;  ushort_t* ysb = outb + 16384;
  float*    outf = (float*)dout;     float*    ysf = outf + 16384;

  // Software-pipelined xi: preload step 0, prefetch t+1 inside the loop so the
  // global-load latency hides under the 192-fdot2 issue window.
  float xr, xz, xn;
  {
    const _Float16* xp = xi + (size_t)b * H3_;
    xr = (float)xp[cc];
    xz = (float)xp[256 + cc];
    xn = (float)xp[512 + cc];
  }

  for (int t = 0; t < Tc; t++){
    barrier_lgkm();                               // hbuf[t&1] ready for all waves

    float nxr = 0.f, nxz = 0.f, nxn = 0.f;
    if (t + 1 < Tc){
      const _Float16* xp = xi + ((size_t)(t + 1) * 64 + b) * H3_;
      nxr = (float)xp[cc];
      nxz = (float)xp[256 + cc];
      nxn = (float)xp[512 + cc];
    }

    const h8* hp = (const h8*)&hbuf[t & 1][hh * 128];
    float ar = 0.f, az = 0.f, an = 0.f;
    dot_block(hp, wr, wz, wn, ar, az, an);

    float Sr = xor1_add(ar) + br + xr;
    float Sz = xor1_add(az) + bz + xz;
    float Sn = xor1_add(an) + bn;
    float r = sigm_(Sr);
    float z = sigm_(Sz);
    float n = tanh_(xn + bi + r * Sn);
    float hnew = (1.0f - z) * n + z * hprev;
    hprev = hnew;

    if (hh == 0){                                 // writes go to the OTHER buffer
      hbuf[(t & 1) ^ 1][cc] = (_Float16)hnew;
      size_t yi = ((size_t)(t0 + t) * 64 + b) * 256 + cc;
      if (f32) ysf[yi] = hnew; else ysb[yi] = f2bf(hnew);
    }

    xr = nxr; xz = nxz; xn = nxn;
  }

  if (hh == 0){
    h_state[b * 256 + cc] = hprev;
    if (t0 + Tc == T_TOT){
      if (f32) outf[b * 256 + cc] = hprev;
      else     outb[b * 256 + cc] = f2bf(hprev);
    }
  }
}

extern "C" void kernel_launch(void* const* d_in, const int* in_sizes, int n_in,
                              void* d_out, int out_size, void* d_ws, size_t ws_size,
                              hipStream_t stream)
{
  const void* c0  = d_in[0];
  const void* xs  = d_in[1];
  const void* Wi  = d_in[2];
  const void* Wh  = d_in[3];
  const void* bh  = d_in[4];
  const void* bin = d_in[5];

  int*      flag    = (int*)d_ws;
  float*    h_state = (float*)((char*)d_ws + 512);
  _Float16* xi      = (_Float16*)((char*)d_ws + 512 + 65536);

  dtype_probe<<<dim3(1), dim3(64), 0, stream>>>(Wh, flag);

  const size_t base_off = 512 + 65536;
  const size_t per_t = (size_t)B_ * H3_ * sizeof(_Float16);   // 98304 B
  long avail_t = (ws_size > base_off + per_t)
                   ? (long)((ws_size - base_off) / per_t) : 1;
  if (avail_t < 1) avail_t = 1;
  if (avail_t > T_TOT) avail_t = T_TOT;
  int Tc = 1;
  while ((long)Tc * 2 <= avail_t) Tc <<= 1;                   // divides 2048

  for (int t0 = 0; t0 < T_TOT; t0 += Tc){
    gru_xproj<<<dim3(256), dim3(512), 0, stream>>>(xs, Wi, xi, flag, t0, Tc);
    gru_rec<<<dim3(64), dim3(512), 0, stream>>>(xi, Wh, bh, bin, c0, h_state,
                                                d_out, flag, t0, Tc);
  }
}